// Round 13
// baseline (769.836 us; speedup 1.0000x reference)
//
#include <hip/hip_runtime.h>

#define LRELU(x) ((x) > 0.f ? (x) : 0.01f * (x))

constexpr int BSH = 8;            // 256 dst-nodes per bucket
constexpr int MAXBK = 512;        // max buckets (N <= 131072)

typedef int iv4 __attribute__((ext_vector_type(4)));

// ---- bf16 pack/unpack helpers ----
__device__ __forceinline__ unsigned pk_bf16(float a, float b) {
    unsigned ua = __float_as_uint(a), ub = __float_as_uint(b);
    unsigned ra = (ua + 0x7fffu + ((ua >> 16) & 1u)) >> 16;
    unsigned rb = (ub + 0x7fffu + ((ub >> 16) & 1u)) & 0xffff0000u;
    return ra | rb;
}
__device__ __forceinline__ float lo_bf16(unsigned w) { return __uint_as_float(w << 16); }
__device__ __forceinline__ float hi_bf16(unsigned w) { return __uint_as_float(w & 0xffff0000u); }

// ---- bucket histogram (LDS-privatized) ----
__global__ void k_bhist(const int* __restrict__ col, int* __restrict__ ghist, int E) {
    __shared__ int lh[MAXBK];
    for (int i = threadIdx.x; i < MAXBK; i += blockDim.x) lh[i] = 0;
    __syncthreads();
    int chunk = (E + gridDim.x - 1) / gridDim.x;
    int c0 = blockIdx.x * chunk, c1 = min(E, c0 + chunk);
    for (int e = c0 + threadIdx.x; e < c1; e += blockDim.x)
        atomicAdd(&lh[col[e] >> BSH], 1);
    __syncthreads();
    for (int i = threadIdx.x; i < MAXBK; i += blockDim.x) {
        int v = lh[i];
        if (v) atomicAdd(&ghist[i], v);
    }
}

// ---- exclusive scan of bucket counts -> bbase, gcur ----
__global__ void k_bscan(const int* __restrict__ ghist, int* __restrict__ bbase,
                        int* __restrict__ gcur, int nbk, int E) {
    __shared__ int sm[MAXBK];
    int tid = threadIdx.x;
    int v = (tid < nbk) ? ghist[tid] : 0;
    sm[tid] = v;
    __syncthreads();
    for (int off = 1; off < MAXBK; off <<= 1) {
        int t = (tid >= off) ? sm[tid - off] : 0;
        __syncthreads();
        sm[tid] += t;
        __syncthreads();
    }
    if (tid < nbk) {
        int excl = sm[tid] - v;
        bbase[tid] = excl;
        gcur[tid] = excl;
    }
    if (tid == 0) bbase[nbk] = E;
}

// ---- partition edges into buckets; per-wg claimed contiguous runs ----
// tmp entry: { src | (dstLow8 << 17), ea_bits }
__global__ void k_part(const int* __restrict__ row, const int* __restrict__ col,
                       const float* __restrict__ ea, int* __restrict__ gcur,
                       int2* __restrict__ tmp, int E) {
    __shared__ int lcnt[MAXBK];
    __shared__ int lbase[MAXBK];
    __shared__ int lcur[MAXBK];
    for (int i = threadIdx.x; i < MAXBK; i += blockDim.x) { lcnt[i] = 0; lcur[i] = 0; }
    __syncthreads();
    int chunk = (E + gridDim.x - 1) / gridDim.x;
    int c0 = blockIdx.x * chunk, c1 = min(E, c0 + chunk);
    for (int e = c0 + threadIdx.x; e < c1; e += blockDim.x)
        atomicAdd(&lcnt[col[e] >> BSH], 1);
    __syncthreads();
    for (int b = threadIdx.x; b < MAXBK; b += blockDim.x) {
        int c = lcnt[b];
        lbase[b] = c ? atomicAdd(&gcur[b], c) : 0;
    }
    __syncthreads();
    for (int e = c0 + threadIdx.x; e < c1; e += blockDim.x) {
        int cc = col[e];
        int b = cc >> BSH;
        int r = atomicAdd(&lcur[b], 1);
        tmp[lbase[b] + r] = make_int2(row[e] | ((cc & 255) << 17), __float_as_int(ea[e]));
    }
}

// ---- per-bucket CSR build ----
__global__ void k_build(const int* __restrict__ bbase, const int2* __restrict__ tmp,
                        int* __restrict__ rowptr, float* __restrict__ dinv,
                        int2* __restrict__ pairs, int N, int E) {
    __shared__ int ncnt[256], noff[256], ncur[256], scn[256];
    __shared__ float ndeg[256];
    int tid = threadIdx.x;
    int bg = blockIdx.x;
    int node0 = bg << BSH;
    int s = bbase[bg], e = bbase[bg + 1];
    ncnt[tid] = 0; ncur[tid] = 0; ndeg[tid] = 0.f;
    __syncthreads();
    for (int p = s + tid; p < e; p += 256) {
        int2 u = tmp[p];
        int nl = (u.x >> 17) & 255;
        atomicAdd(&ncnt[nl], 1);
        atomicAdd(&ndeg[nl], __int_as_float(u.y));
    }
    __syncthreads();
    int v = ncnt[tid];
    scn[tid] = v;
    __syncthreads();
    for (int off = 1; off < 256; off <<= 1) {
        int t = (tid >= off) ? scn[tid - off] : 0;
        __syncthreads();
        scn[tid] += t;
        __syncthreads();
    }
    {
        int excl = scn[tid] - v;
        noff[tid] = excl;
        int node = node0 + tid;
        if (node < N) {
            rowptr[node] = s + excl;
            float d = ndeg[tid];
            dinv[node] = d > 0.f ? rsqrtf(fmaxf(d, 1e-12f)) : 0.f;
        }
    }
    if (bg == gridDim.x - 1 && tid == 0) rowptr[N] = E;
    __syncthreads();
    for (int p = s + tid; p < e; p += 256) {
        int2 u = tmp[p];
        int nl = (u.x >> 17) & 255;
        int r = atomicAdd(&ncur[nl], 1);
        pairs[s + noff[nl] + r] = make_int2(u.x & 0x1FFFF, u.y);
    }
}

// ---- read-in MLP: h = lrelu([state,action]@W_in+b_in); zrec0=bf16(h), v0=bf16(dinv*h) ----
__global__ void k_inmlp(const float* __restrict__ state, const float* __restrict__ action,
                        const float* __restrict__ Win, const float* __restrict__ bin,
                        const float* __restrict__ dinv,
                        unsigned* __restrict__ zrec0, unsigned* __restrict__ v0, int N) {
    int t = blockIdx.x * blockDim.x + threadIdx.x;
    int i = t >> 5, c = t & 31;
    if (i >= N) return;
    float acc = bin[c];
#pragma unroll
    for (int d = 0; d < 8; ++d) acc += state[i * 8 + d] * Win[d * 32 + c];
#pragma unroll
    for (int d = 0; d < 2; ++d) acc += action[i * 2 + d] * Win[(8 + d) * 32 + c];
    float hv = LRELU(acc);
    float ho = __shfl_xor(hv, 1, 32);
    float vv = dinv[i] * hv;
    float vo = __shfl_xor(vv, 1, 32);
    if ((c & 1) == 0) {
        int j = c >> 1;
        zrec0[(size_t)i * 16 + j] = pk_bf16(hv, ho);
        v0[(size_t)i * 16 + j]    = pk_bf16(vv, vo);
    }
}

__device__ __forceinline__ void edge_acc(float4& tv, float w, uint2 x) {
    tv.x += w * lo_bf16(x.x); tv.y += w * hi_bf16(x.x);
    tv.z += w * lo_bf16(x.y); tv.w += w * hi_bf16(x.y);
}

// ---- pure propagate tap: zrec_k = bf16(dinv*t), vout_k = bf16(dinv^2*t) ----
// 8 lanes per node; lane q owns channels 4q..4q+3 (one uint2 of the 64B row)
__global__ void k_tap(const int* __restrict__ rowptr, const int2* __restrict__ pairs,
                      const uint2* __restrict__ vin, const float* __restrict__ dinv,
                      uint2* __restrict__ zrec, uint2* __restrict__ vout,
                      int N, int last) {
    int t = blockIdx.x * blockDim.x + threadIdx.x;
    int g = t >> 3, q = t & 7;
    if (g >= N) return;
    int s = rowptr[g], e = rowptr[g + 1];
    float4 tv = {0.f, 0.f, 0.f, 0.f};
    int p = s;
    if ((p & 1) && p < e) {                 // peel to 16B-aligned pair index
        int2 pr = pairs[p];
        uint2 x = vin[((size_t)(unsigned)pr.x << 3) + q];
        edge_acc(tv, __int_as_float(pr.y), x);
        ++p;
    }
#pragma unroll 2
    for (; p + 4 <= e; p += 4) {            // 4 edges: 2 nt pair-loads, 4 uint2 gathers
        iv4 pa = __builtin_nontemporal_load((const iv4*)&pairs[p]);
        iv4 pb = __builtin_nontemporal_load((const iv4*)&pairs[p + 2]);
        uint2 x0 = vin[((size_t)(unsigned)pa[0] << 3) + q];
        uint2 x1 = vin[((size_t)(unsigned)pa[2] << 3) + q];
        uint2 x2 = vin[((size_t)(unsigned)pb[0] << 3) + q];
        uint2 x3 = vin[((size_t)(unsigned)pb[2] << 3) + q];
        edge_acc(tv, __int_as_float(pa[1]), x0);
        edge_acc(tv, __int_as_float(pa[3]), x1);
        edge_acc(tv, __int_as_float(pb[1]), x2);
        edge_acc(tv, __int_as_float(pb[3]), x3);
    }
    for (; p < e; ++p) {                    // tail singles
        int2 pr = pairs[p];
        uint2 x = vin[((size_t)(unsigned)pr.x << 3) + q];
        edge_acc(tv, __int_as_float(pr.y), x);
    }
    float di = dinv[g];
    float z0 = di * tv.x, z1 = di * tv.y, z2 = di * tv.z, z3 = di * tv.w;
    zrec[((size_t)g << 3) + q] = make_uint2(pk_bf16(z0, z1), pk_bf16(z2, z3));
    if (!last)
        vout[((size_t)g << 3) + q] = make_uint2(pk_bf16(di * z0, di * z1),
                                                pk_bf16(di * z2, di * z3));
}

// ---- per-layer fused GEMM: o = bias + sum_k zrec_k @ W_k; lrelu; emit next state ----
// 8 lanes/node; lane q computes cols 4q..4q+3; zrec rows read directly (broadcast)
__global__ void k_gemm(const uint2* __restrict__ z0, const uint2* __restrict__ z1,
                       const uint2* __restrict__ z2, const uint2* __restrict__ z3,
                       const uint2* __restrict__ z4, const float* __restrict__ dinv,
                       const float* __restrict__ Wl, const float* __restrict__ bias,
                       const float* __restrict__ Wout, const float* __restrict__ bout,
                       unsigned* __restrict__ zrec0n, unsigned* __restrict__ v0n,
                       float* __restrict__ yv, int N, int lastL) {
    int t = blockIdx.x * blockDim.x + threadIdx.x;
    int g = t >> 3, q = t & 7;
    if (g >= N) return;
    float4 acc = *(const float4*)&bias[4 * q];
#define DO_K(ZP, KI)                                                            \
    {                                                                           \
        const uint2* zr = (ZP) + ((size_t)g << 3);                              \
        const float* W = Wl + (KI) * 1024;                                      \
        _Pragma("unroll")                                                       \
        for (int jj = 0; jj < 8; ++jj) {                                        \
            uint2 u = zr[jj];                                                   \
            float a0 = lo_bf16(u.x), a1 = hi_bf16(u.x);                         \
            float a2 = lo_bf16(u.y), a3 = hi_bf16(u.y);                         \
            const float4 w0 = *(const float4*)&W[(4 * jj + 0) * 32 + 4 * q];    \
            const float4 w1 = *(const float4*)&W[(4 * jj + 1) * 32 + 4 * q];    \
            const float4 w2 = *(const float4*)&W[(4 * jj + 2) * 32 + 4 * q];    \
            const float4 w3 = *(const float4*)&W[(4 * jj + 3) * 32 + 4 * q];    \
            acc.x += a0 * w0.x + a1 * w1.x + a2 * w2.x + a3 * w3.x;             \
            acc.y += a0 * w0.y + a1 * w1.y + a2 * w2.y + a3 * w3.y;             \
            acc.z += a0 * w0.z + a1 * w1.z + a2 * w2.z + a3 * w3.z;             \
            acc.w += a0 * w0.w + a1 * w1.w + a2 * w2.w + a3 * w3.w;             \
        }                                                                       \
    }
    DO_K(z0, 0) DO_K(z1, 1) DO_K(z2, 2) DO_K(z3, 3) DO_K(z4, 4)
#undef DO_K
    float h0 = LRELU(acc.x), h1 = LRELU(acc.y), h2 = LRELU(acc.z), h3 = LRELU(acc.w);
    if (!lastL) {
        float di = dinv[g];
        ((uint2*)zrec0n)[((size_t)g << 3) + q] = make_uint2(pk_bf16(h0, h1), pk_bf16(h2, h3));
        ((uint2*)v0n)[((size_t)g << 3) + q] = make_uint2(pk_bf16(di * h0, di * h1),
                                                         pk_bf16(di * h2, di * h3));
    } else {
        const float4 w4 = *(const float4*)&Wout[4 * q];
        float v = h0 * w4.x + h1 * w4.y + h2 * w4.z + h3 * w4.w;
        v += __shfl_xor(v, 4, 8);
        v += __shfl_xor(v, 2, 8);
        v += __shfl_xor(v, 1, 8);
        if (q == 0) yv[g] = v + bout[0];
    }
}

// ---- segmented mean over sorted batch: one block per graph ----
__global__ void k_segmean(const float* __restrict__ y, const int* __restrict__ batch,
                          float* __restrict__ out, int N) {
    int b = blockIdx.x;
    __shared__ int slo, shi;
    if (threadIdx.x == 0) {
        int lo = 0, hi = N;
        while (lo < hi) { int m = (lo + hi) >> 1; if (batch[m] < b) lo = m + 1; else hi = m; }
        slo = lo;
        hi = N;
        while (lo < hi) { int m = (lo + hi) >> 1; if (batch[m] < b + 1) lo = m + 1; else hi = m; }
        shi = lo;
    }
    __syncthreads();
    int lo = slo, hi = shi;
    float sum = 0.f;
    for (int i = lo + threadIdx.x; i < hi; i += blockDim.x) sum += y[i];
    __shared__ float sm[256];
    sm[threadIdx.x] = sum;
    __syncthreads();
    for (int o = 128; o; o >>= 1) {
        if (threadIdx.x < o) sm[threadIdx.x] += sm[threadIdx.x + o];
        __syncthreads();
    }
    if (threadIdx.x == 0) out[b] = sm[0] / fmaxf((float)(hi - lo), 1.0f);
}

static inline size_t algn(size_t x) { return (x + 255) & ~(size_t)255; }

extern "C" void kernel_launch(void* const* d_in, const int* in_sizes, int n_in,
                              void* d_out, int out_size, void* d_ws, size_t ws_size,
                              hipStream_t stream) {
    const float* state  = (const float*)d_in[0];
    const float* action = (const float*)d_in[1];
    const int*   eidx   = (const int*)d_in[2];
    const float* eattr  = (const float*)d_in[3];
    const int*   batch  = (const int*)d_in[4];
    const float* Win    = (const float*)d_in[5];
    const float* bin    = (const float*)d_in[6];
    const float* Wtaps  = (const float*)d_in[7];
    const float* bgnn   = (const float*)d_in[8];
    const float* Wout   = (const float*)d_in[9];
    const float* bout   = (const float*)d_in[10];
    float* out = (float*)d_out;

    const int N = in_sizes[0] / 8;       // SD=8
    const int E = in_sizes[3];
    const int B = out_size;
    const int K = 4, L = 2;
    const int NBK = (N + 255) >> BSH;

    const int* row = eidx;
    const int* col = eidx + E;

    // ---- workspace layout ----
    char* base = (char*)d_ws;
    int* ghist = (int*)base;                    // MAXBK, zeroed
    int* gcur  = ghist + MAXBK;                 // written by bscan
    size_t zbytes = (size_t)MAXBK * 4;
    char* p = base + algn((size_t)2 * MAXBK * 4);
    int*   bbase  = (int*)p;  p += algn((size_t)(MAXBK + 1) * 4);
    int*   rowptr = (int*)p;  p += algn((size_t)(N + 1) * 4);
    float* dinv   = (float*)p; p += algn((size_t)N * 4);
    int2*  pairs  = (int2*)p;  p += algn((size_t)E * 8);
    // zrec0..3 region (4 * N*64B) aliased by tmp (E*8B)
    size_t region = (size_t)N * 256;
    if ((size_t)E * 8 > region) region = (size_t)E * 8;
    unsigned* zrec0 = (unsigned*)p;
    unsigned* zrec1 = (unsigned*)(p + (size_t)N * 64);
    unsigned* zrec2 = (unsigned*)(p + (size_t)N * 128);
    unsigned* zrec3 = (unsigned*)(p + (size_t)N * 192);
    int2*     tmp   = (int2*)p;  p += algn(region);
    unsigned* zrec4 = (unsigned*)p; p += algn((size_t)N * 64);
    unsigned* vh    = (unsigned*)p; p += algn((size_t)N * 64);
    unsigned* vA    = (unsigned*)p; p += algn((size_t)N * 64);
    unsigned* vB    = (unsigned*)p; p += algn((size_t)N * 64);
    float*    yv    = (float*)p;    p += algn((size_t)N * 4);
    (void)ws_size; (void)n_in;

    const int BT = 256;
    const int gNC = ((size_t)N * 32 + BT - 1) / BT;
    const int gN8 = ((size_t)N * 8 + BT - 1) / BT;

    hipMemsetAsync(d_ws, 0, zbytes, stream);

    k_bhist<<<512, BT, 0, stream>>>(col, ghist, E);
    k_bscan<<<1, MAXBK, 0, stream>>>(ghist, bbase, gcur, NBK, E);
    k_part<<<256, 1024, 0, stream>>>(row, col, eattr, gcur, tmp, E);
    k_build<<<NBK, 256, 0, stream>>>(bbase, tmp, rowptr, dinv, pairs, N, E);

    k_inmlp<<<gNC, BT, 0, stream>>>(state, action, Win, bin, dinv, zrec0, vh, N);

    unsigned* zr[5] = {zrec0, zrec1, zrec2, zrec3, zrec4};
    for (int l = 0; l < L; ++l) {
        const float* Wl = Wtaps + (size_t)l * (K + 1) * 1024;
        const float* bl = bgnn + (size_t)l * 32;
        const unsigned* vin = vh;
        for (int k = 1; k <= K; ++k) {
            int last = (k == K);
            unsigned* vout = (k & 1) ? vA : vB;
            k_tap<<<gN8, BT, 0, stream>>>(rowptr, pairs, (const uint2*)vin, dinv,
                                          (uint2*)zr[k], (uint2*)vout, N, last);
            vin = vout;
        }
        k_gemm<<<gN8, BT, 0, stream>>>((const uint2*)zr[0], (const uint2*)zr[1],
                                       (const uint2*)zr[2], (const uint2*)zr[3],
                                       (const uint2*)zr[4], dinv, Wl, bl, Wout, bout,
                                       zrec0, vh, yv, N, l == L - 1);
    }

    k_segmean<<<B, 256, 0, stream>>>(yv, batch, out, N);
}

// Round 14
// 656.328 us; speedup vs baseline: 1.1729x; 1.1729x over previous
//
#include <hip/hip_runtime.h>

#define LRELU(x) ((x) > 0.f ? (x) : 0.01f * (x))

constexpr int BSH = 8;            // 256 dst-nodes per bucket
constexpr int MAXBK = 512;        // max buckets (N <= 131072)

typedef int iv4 __attribute__((ext_vector_type(4)));

// ---- bf16 pack/unpack helpers ----
__device__ __forceinline__ unsigned pk_bf16(float a, float b) {
    unsigned ua = __float_as_uint(a), ub = __float_as_uint(b);
    unsigned ra = (ua + 0x7fffu + ((ua >> 16) & 1u)) >> 16;
    unsigned rb = (ub + 0x7fffu + ((ub >> 16) & 1u)) & 0xffff0000u;
    return ra | rb;
}
__device__ __forceinline__ float lo_bf16(unsigned w) { return __uint_as_float(w << 16); }
__device__ __forceinline__ float hi_bf16(unsigned w) { return __uint_as_float(w & 0xffff0000u); }

// ---- bucket histogram (LDS-privatized) ----
__global__ void k_bhist(const int* __restrict__ col, int* __restrict__ ghist, int E) {
    __shared__ int lh[MAXBK];
    for (int i = threadIdx.x; i < MAXBK; i += blockDim.x) lh[i] = 0;
    __syncthreads();
    int chunk = (E + gridDim.x - 1) / gridDim.x;
    int c0 = blockIdx.x * chunk, c1 = min(E, c0 + chunk);
    for (int e = c0 + threadIdx.x; e < c1; e += blockDim.x)
        atomicAdd(&lh[col[e] >> BSH], 1);
    __syncthreads();
    for (int i = threadIdx.x; i < MAXBK; i += blockDim.x) {
        int v = lh[i];
        if (v) atomicAdd(&ghist[i], v);
    }
}

// ---- exclusive scan of bucket counts -> bbase, gcur ----
__global__ void k_bscan(const int* __restrict__ ghist, int* __restrict__ bbase,
                        int* __restrict__ gcur, int nbk, int E) {
    __shared__ int sm[MAXBK];
    int tid = threadIdx.x;
    int v = (tid < nbk) ? ghist[tid] : 0;
    sm[tid] = v;
    __syncthreads();
    for (int off = 1; off < MAXBK; off <<= 1) {
        int t = (tid >= off) ? sm[tid - off] : 0;
        __syncthreads();
        sm[tid] += t;
        __syncthreads();
    }
    if (tid < nbk) {
        int excl = sm[tid] - v;
        bbase[tid] = excl;
        gcur[tid] = excl;
    }
    if (tid == 0) bbase[nbk] = E;
}

// ---- partition edges into buckets; per-wg claimed contiguous runs ----
// tmp entry: { src | (dstLow8 << 17), ea_bits }
__global__ void k_part(const int* __restrict__ row, const int* __restrict__ col,
                       const float* __restrict__ ea, int* __restrict__ gcur,
                       int2* __restrict__ tmp, int E) {
    __shared__ int lcnt[MAXBK];
    __shared__ int lbase[MAXBK];
    __shared__ int lcur[MAXBK];
    for (int i = threadIdx.x; i < MAXBK; i += blockDim.x) { lcnt[i] = 0; lcur[i] = 0; }
    __syncthreads();
    int chunk = (E + gridDim.x - 1) / gridDim.x;
    int c0 = blockIdx.x * chunk, c1 = min(E, c0 + chunk);
    for (int e = c0 + threadIdx.x; e < c1; e += blockDim.x)
        atomicAdd(&lcnt[col[e] >> BSH], 1);
    __syncthreads();
    for (int b = threadIdx.x; b < MAXBK; b += blockDim.x) {
        int c = lcnt[b];
        lbase[b] = c ? atomicAdd(&gcur[b], c) : 0;
    }
    __syncthreads();
    for (int e = c0 + threadIdx.x; e < c1; e += blockDim.x) {
        int cc = col[e];
        int b = cc >> BSH;
        int r = atomicAdd(&lcur[b], 1);
        tmp[lbase[b] + r] = make_int2(row[e] | ((cc & 255) << 17), __float_as_int(ea[e]));
    }
}

// ---- per-bucket CSR build ----
__global__ void k_build(const int* __restrict__ bbase, const int2* __restrict__ tmp,
                        int* __restrict__ rowptr, float* __restrict__ dinv,
                        int2* __restrict__ pairs, int N, int E) {
    __shared__ int ncnt[256], noff[256], ncur[256], scn[256];
    __shared__ float ndeg[256];
    int tid = threadIdx.x;
    int bg = blockIdx.x;
    int node0 = bg << BSH;
    int s = bbase[bg], e = bbase[bg + 1];
    ncnt[tid] = 0; ncur[tid] = 0; ndeg[tid] = 0.f;
    __syncthreads();
    for (int p = s + tid; p < e; p += 256) {
        int2 u = tmp[p];
        int nl = (u.x >> 17) & 255;
        atomicAdd(&ncnt[nl], 1);
        atomicAdd(&ndeg[nl], __int_as_float(u.y));
    }
    __syncthreads();
    int v = ncnt[tid];
    scn[tid] = v;
    __syncthreads();
    for (int off = 1; off < 256; off <<= 1) {
        int t = (tid >= off) ? scn[tid - off] : 0;
        __syncthreads();
        scn[tid] += t;
        __syncthreads();
    }
    {
        int excl = scn[tid] - v;
        noff[tid] = excl;
        int node = node0 + tid;
        if (node < N) {
            rowptr[node] = s + excl;
            float d = ndeg[tid];
            dinv[node] = d > 0.f ? rsqrtf(fmaxf(d, 1e-12f)) : 0.f;
        }
    }
    if (bg == gridDim.x - 1 && tid == 0) rowptr[N] = E;
    __syncthreads();
    for (int p = s + tid; p < e; p += 256) {
        int2 u = tmp[p];
        int nl = (u.x >> 17) & 255;
        int r = atomicAdd(&ncur[nl], 1);
        pairs[s + noff[nl] + r] = make_int2(u.x & 0x1FFFF, u.y);
    }
}

// ---- read-in MLP: h = lrelu([state,action]@W_in+b_in); zrec0=bf16(h), v0=bf16(dinv*h) ----
__global__ void k_inmlp(const float* __restrict__ state, const float* __restrict__ action,
                        const float* __restrict__ Win, const float* __restrict__ bin,
                        const float* __restrict__ dinv,
                        unsigned* __restrict__ zrec0, unsigned* __restrict__ v0, int N) {
    int t = blockIdx.x * blockDim.x + threadIdx.x;
    int i = t >> 5, c = t & 31;
    if (i >= N) return;
    float acc = bin[c];
#pragma unroll
    for (int d = 0; d < 8; ++d) acc += state[i * 8 + d] * Win[d * 32 + c];
#pragma unroll
    for (int d = 0; d < 2; ++d) acc += action[i * 2 + d] * Win[(8 + d) * 32 + c];
    float hv = LRELU(acc);
    float ho = __shfl_xor(hv, 1, 32);
    float vv = dinv[i] * hv;
    float vo = __shfl_xor(vv, 1, 32);
    if ((c & 1) == 0) {
        int j = c >> 1;
        zrec0[(size_t)i * 16 + j] = pk_bf16(hv, ho);
        v0[(size_t)i * 16 + j]    = pk_bf16(vv, vo);
    }
}

__device__ __forceinline__ void edge_acc(float4& tv, float w, uint2 x) {
    tv.x += w * lo_bf16(x.x); tv.y += w * hi_bf16(x.x);
    tv.z += w * lo_bf16(x.y); tv.w += w * hi_bf16(x.y);
}

// ---- pure propagate tap: zrec_k = bf16(dinv*t), vout_k = bf16(dinv^2*t) ----
// 8 lanes per node; lane q owns channels 4q..4q+3 (one uint2 of the 64B row)
__global__ void k_tap(const int* __restrict__ rowptr, const int2* __restrict__ pairs,
                      const uint2* __restrict__ vin, const float* __restrict__ dinv,
                      uint2* __restrict__ zrec, uint2* __restrict__ vout,
                      int N, int last) {
    int t = blockIdx.x * blockDim.x + threadIdx.x;
    int g = t >> 3, q = t & 7;
    if (g >= N) return;
    int s = rowptr[g], e = rowptr[g + 1];
    float4 tv = {0.f, 0.f, 0.f, 0.f};
    int p = s;
    if ((p & 1) && p < e) {                 // peel to 16B-aligned pair index
        int2 pr = pairs[p];
        uint2 x = vin[((size_t)(unsigned)pr.x << 3) + q];
        edge_acc(tv, __int_as_float(pr.y), x);
        ++p;
    }
#pragma unroll 2
    for (; p + 4 <= e; p += 4) {            // 4 edges: 2 nt pair-loads, 4 uint2 gathers
        iv4 pa = __builtin_nontemporal_load((const iv4*)&pairs[p]);
        iv4 pb = __builtin_nontemporal_load((const iv4*)&pairs[p + 2]);
        uint2 x0 = vin[((size_t)(unsigned)pa[0] << 3) + q];
        uint2 x1 = vin[((size_t)(unsigned)pa[2] << 3) + q];
        uint2 x2 = vin[((size_t)(unsigned)pb[0] << 3) + q];
        uint2 x3 = vin[((size_t)(unsigned)pb[2] << 3) + q];
        edge_acc(tv, __int_as_float(pa[1]), x0);
        edge_acc(tv, __int_as_float(pa[3]), x1);
        edge_acc(tv, __int_as_float(pb[1]), x2);
        edge_acc(tv, __int_as_float(pb[3]), x3);
    }
    for (; p < e; ++p) {                    // tail singles
        int2 pr = pairs[p];
        uint2 x = vin[((size_t)(unsigned)pr.x << 3) + q];
        edge_acc(tv, __int_as_float(pr.y), x);
    }
    float di = dinv[g];
    float z0 = di * tv.x, z1 = di * tv.y, z2 = di * tv.z, z3 = di * tv.w;
    zrec[((size_t)g << 3) + q] = make_uint2(pk_bf16(z0, z1), pk_bf16(z2, z3));
    if (!last)
        vout[((size_t)g << 3) + q] = make_uint2(pk_bf16(di * z0, di * z1),
                                                pk_bf16(di * z2, di * z3));
}

// acc(4 cols) += z(row, spread over 8 lanes as float4) @ W(32x32), cols 4q..4q+3
__device__ __forceinline__ void mm_acc(float4& acc, float4 zq,
                                       const float* __restrict__ W, int q) {
#pragma unroll
    for (int a = 0; a < 8; ++a) {
        float z0 = __shfl(zq.x, a, 8), z1 = __shfl(zq.y, a, 8);
        float z2 = __shfl(zq.z, a, 8), z3 = __shfl(zq.w, a, 8);
        const float4 w0 = *(const float4*)&W[(4 * a + 0) * 32 + 4 * q];
        const float4 w1 = *(const float4*)&W[(4 * a + 1) * 32 + 4 * q];
        const float4 w2 = *(const float4*)&W[(4 * a + 2) * 32 + 4 * q];
        const float4 w3 = *(const float4*)&W[(4 * a + 3) * 32 + 4 * q];
        acc.x += z0 * w0.x + z1 * w1.x + z2 * w2.x + z3 * w3.x;
        acc.y += z0 * w0.y + z1 * w1.y + z2 * w2.y + z3 * w3.y;
        acc.z += z0 * w0.z + z1 * w1.z + z2 * w2.z + z3 * w3.z;
        acc.w += z0 * w0.w + z1 * w1.w + z2 * w2.w + z3 * w3.w;
    }
}

// ---- per-layer fused GEMM: o = bias + sum_k zrec_k @ W_k; lrelu; emit next state ----
// zrec stacked [5][N][8] uint2; lane q reads ONLY its own uint2 per tap (coalesced),
// 8-lane shuffle broadcast inside mm_acc. Outer k-loop kept rolled (no spills).
__global__ __launch_bounds__(256, 4)
void k_gemm(const uint2* __restrict__ zrec, const float* __restrict__ dinv,
            const float* __restrict__ Wl, const float* __restrict__ bias,
            const float* __restrict__ Wout, const float* __restrict__ bout,
            unsigned* __restrict__ zrec0n, unsigned* __restrict__ v0n,
            float* __restrict__ yv, int N, int lastL) {
    int t = blockIdx.x * blockDim.x + threadIdx.x;
    int g = t >> 3, q = t & 7;
    if (g >= N) return;
    float4 acc = *(const float4*)&bias[4 * q];
    const uint2* zown = zrec + ((size_t)g << 3) + q;
    size_t kstride = (size_t)N << 3;
#pragma unroll 1
    for (int k = 0; k < 5; ++k) {
        uint2 u = zown[(size_t)k * kstride];
        float4 z = {lo_bf16(u.x), hi_bf16(u.x), lo_bf16(u.y), hi_bf16(u.y)};
        mm_acc(acc, z, Wl + (size_t)k * 1024, q);
    }
    float h0 = LRELU(acc.x), h1 = LRELU(acc.y), h2 = LRELU(acc.z), h3 = LRELU(acc.w);
    if (!lastL) {
        float di = dinv[g];
        ((uint2*)zrec0n)[((size_t)g << 3) + q] = make_uint2(pk_bf16(h0, h1), pk_bf16(h2, h3));
        ((uint2*)v0n)[((size_t)g << 3) + q] = make_uint2(pk_bf16(di * h0, di * h1),
                                                         pk_bf16(di * h2, di * h3));
    } else {
        const float4 w4 = *(const float4*)&Wout[4 * q];
        float v = h0 * w4.x + h1 * w4.y + h2 * w4.z + h3 * w4.w;
        v += __shfl_xor(v, 4, 8);
        v += __shfl_xor(v, 2, 8);
        v += __shfl_xor(v, 1, 8);
        if (q == 0) yv[g] = v + bout[0];
    }
}

// ---- segmented mean over sorted batch: one block per graph ----
__global__ void k_segmean(const float* __restrict__ y, const int* __restrict__ batch,
                          float* __restrict__ out, int N) {
    int b = blockIdx.x;
    __shared__ int slo, shi;
    if (threadIdx.x == 0) {
        int lo = 0, hi = N;
        while (lo < hi) { int m = (lo + hi) >> 1; if (batch[m] < b) lo = m + 1; else hi = m; }
        slo = lo;
        hi = N;
        while (lo < hi) { int m = (lo + hi) >> 1; if (batch[m] < b + 1) lo = m + 1; else hi = m; }
        shi = lo;
    }
    __syncthreads();
    int lo = slo, hi = shi;
    float sum = 0.f;
    for (int i = lo + threadIdx.x; i < hi; i += blockDim.x) sum += y[i];
    __shared__ float sm[256];
    sm[threadIdx.x] = sum;
    __syncthreads();
    for (int o = 128; o; o >>= 1) {
        if (threadIdx.x < o) sm[threadIdx.x] += sm[threadIdx.x + o];
        __syncthreads();
    }
    if (threadIdx.x == 0) out[b] = sm[0] / fmaxf((float)(hi - lo), 1.0f);
}

static inline size_t algn(size_t x) { return (x + 255) & ~(size_t)255; }

extern "C" void kernel_launch(void* const* d_in, const int* in_sizes, int n_in,
                              void* d_out, int out_size, void* d_ws, size_t ws_size,
                              hipStream_t stream) {
    const float* state  = (const float*)d_in[0];
    const float* action = (const float*)d_in[1];
    const int*   eidx   = (const int*)d_in[2];
    const float* eattr  = (const float*)d_in[3];
    const int*   batch  = (const int*)d_in[4];
    const float* Win    = (const float*)d_in[5];
    const float* bin    = (const float*)d_in[6];
    const float* Wtaps  = (const float*)d_in[7];
    const float* bgnn   = (const float*)d_in[8];
    const float* Wout   = (const float*)d_in[9];
    const float* bout   = (const float*)d_in[10];
    float* out = (float*)d_out;

    const int N = in_sizes[0] / 8;       // SD=8
    const int E = in_sizes[3];
    const int B = out_size;
    const int K = 4, L = 2;
    const int NBK = (N + 255) >> BSH;

    const int* row = eidx;
    const int* col = eidx + E;

    // ---- workspace layout ----
    char* base = (char*)d_ws;
    int* ghist = (int*)base;                    // MAXBK, zeroed
    int* gcur  = ghist + MAXBK;                 // written by bscan
    size_t zbytes = (size_t)MAXBK * 4;
    char* p = base + algn((size_t)2 * MAXBK * 4);
    int*   bbase  = (int*)p;  p += algn((size_t)(MAXBK + 1) * 4);
    int*   rowptr = (int*)p;  p += algn((size_t)(N + 1) * 4);
    float* dinv   = (float*)p; p += algn((size_t)N * 4);
    int2*  pairs  = (int2*)p;  p += algn((size_t)E * 8);
    // zrec stacked [5][N][16 u32] (5*N*64B) aliased by tmp (E*8B)
    size_t region = (size_t)N * 320;
    if ((size_t)E * 8 > region) region = (size_t)E * 8;
    unsigned* zrec = (unsigned*)p;              // zrec_k at k*N*16 u32
    int2*     tmp  = (int2*)p;  p += algn(region);
    unsigned* vh   = (unsigned*)p; p += algn((size_t)N * 64);
    unsigned* vA   = (unsigned*)p; p += algn((size_t)N * 64);
    unsigned* vB   = (unsigned*)p; p += algn((size_t)N * 64);
    float*    yv   = (float*)p;    p += algn((size_t)N * 4);
    (void)ws_size; (void)n_in;

    const int BT = 256;
    const int gNC = ((size_t)N * 32 + BT - 1) / BT;
    const int gN8 = ((size_t)N * 8 + BT - 1) / BT;

    hipMemsetAsync(d_ws, 0, zbytes, stream);

    k_bhist<<<512, BT, 0, stream>>>(col, ghist, E);
    k_bscan<<<1, MAXBK, 0, stream>>>(ghist, bbase, gcur, NBK, E);
    k_part<<<256, 1024, 0, stream>>>(row, col, eattr, gcur, tmp, E);
    k_build<<<NBK, 256, 0, stream>>>(bbase, tmp, rowptr, dinv, pairs, N, E);

    k_inmlp<<<gNC, BT, 0, stream>>>(state, action, Win, bin, dinv, zrec, vh, N);

    for (int l = 0; l < L; ++l) {
        const float* Wl = Wtaps + (size_t)l * (K + 1) * 1024;
        const float* bl = bgnn + (size_t)l * 32;
        const unsigned* vin = vh;
        for (int k = 1; k <= K; ++k) {
            int last = (k == K);
            unsigned* vout = (k & 1) ? vA : vB;
            k_tap<<<gN8, BT, 0, stream>>>(rowptr, pairs, (const uint2*)vin, dinv,
                                          (uint2*)(zrec + (size_t)k * N * 16),
                                          (uint2*)vout, N, last);
            vin = vout;
        }
        k_gemm<<<gN8, BT, 0, stream>>>((const uint2*)zrec, dinv, Wl, bl, Wout, bout,
                                       zrec, vh, yv, N, l == L - 1);
    }

    k_segmean<<<B, 256, 0, stream>>>(yv, batch, out, N);
}